// Round 7
// baseline (595.904 us; speedup 1.0000x reference)
//
#include <hip/hip_runtime.h>
#include <math.h>

#define I_IMG 3
#define S_SEQ 64
#define C_CH  512
#define H_IN  18
#define W_IN  18
#define HW    324
#define OH 19
#define OW 19
#define NPIX 361
#define PPIX 400          // padded 20x20 partial plane
#define FT 16
#define NITER 5
#define CSPLIT 8
#define CPB 64            // channels per conv_fwd block
#define PLW 24            // fwd LDS plane row stride (floats)
#define PLSZ 580          // fwd LDS plane stride
#define RPW 24            // tr rp row stride
#define TP 54             // pixels per convert tile (324 = 6*54)
#define TSU 516           // convert LDS row stride (ushorts); 1032B rows, 8B-aligned

typedef unsigned int uint;
typedef unsigned short ushort;

__device__ inline float blk_reduce(float v, float* tmp) {
  #pragma unroll
  for (int o = 32; o > 0; o >>= 1) v += __shfl_down(v, o, 64);
  int lane = threadIdx.x & 63;
  int w = threadIdx.x >> 6;
  if (lane == 0) tmp[w] = v;
  __syncthreads();
  float r = 0.f;
  if (threadIdx.x == 0) {
    int nw = (blockDim.x + 63) >> 6;
    for (int k = 0; k < nw; ++k) r += tmp[k];
  }
  return r;
}

__device__ inline ushort f2bf(float f) {   // RNE f32 -> bf16
  uint u = __float_as_uint(f);
  uint r = u + 0x7fffu + ((u >> 16) & 1u);
  return (ushort)(r >> 16);
}

// ---------------------------------------------------------------------------
// convert: feat f32 [n][c][p] -> featB bf16 [n][c][p] + featT bf16 [n][p][c]
// grid (192, 6): block = (n, 54-pixel tile). featT writes fully contiguous.
// ---------------------------------------------------------------------------
__global__ __launch_bounds__(256) void convert_k(
    const float* __restrict__ feat, ushort* __restrict__ featB,
    ushort* __restrict__ featT)
{
  __shared__ __align__(16) ushort tile[TP * TSU];   // 55.7 KB
  int tid = threadIdx.x;
  int n = blockIdx.x;
  int p0 = blockIdx.y * TP;
  const float* src = feat + (size_t)n * C_CH * HW + p0;
  ushort* dB = featB + (size_t)n * C_CH * HW + p0;

  // stage: thread item = (c, pp): float2 (2 px) -> featB + LDS transpose
  for (int idx = tid; idx < C_CH * (TP / 2); idx += 256) {
    int c = idx / (TP / 2), pp = idx - c * (TP / 2);
    float2 v = *(const float2*)(src + (size_t)c * HW + 2 * pp);
    ushort2 b; b.x = f2bf(v.x); b.y = f2bf(v.y);
    *(ushort2*)(dB + (size_t)c * HW + 2 * pp) = b;
    tile[(2 * pp) * TSU + c] = b.x;
    tile[(2 * pp + 1) * TSU + c] = b.y;
  }
  __syncthreads();

  // output: thread item = (p, 4-channel group): uint2 -> contiguous featT
  ushort* dT = featT + ((size_t)n * HW + p0) * C_CH;
  for (int idx = tid; idx < TP * (C_CH / 4); idx += 256) {
    int p = idx >> 7, co = idx & 127;
    uint2 v = *(const uint2*)&tile[p * TSU + 4 * co];
    *(uint2*)(dT + (size_t)p * C_CH + 4 * co) = v;
  }
}

// ---------------------------------------------------------------------------
// prep: distance map -> label_map, sample_weight, a_lo, a_hi; scalars
// ---------------------------------------------------------------------------
__global__ void prep_k(const float* __restrict__ bb,
                       const float* __restrict__ label_w,
                       const float* __restrict__ mask_w,
                       const float* __restrict__ spatial_w,
                       const float* __restrict__ lsl,
                       const float* __restrict__ freg,
                       float* __restrict__ sw, float* __restrict__ lm,
                       float* __restrict__ alo, float* __restrict__ ahi,
                       float* __restrict__ scal)
{
  int n = blockIdx.x;     // n = i*S + s
  int p = threadIdx.x;
  if (n == 0 && p == 0) {
    scal[0] = expf(lsl[0]);                    // step
    scal[1] = fmaxf(freg[0] * freg[0], 1e-6f); // reg
  }
  if (p >= NPIX) return;
  float bx = bb[n * 4 + 0], by = bb[n * 4 + 1];
  float bw = bb[n * 4 + 2], bh = bb[n * 4 + 3];
  float crow = (by + bh * 0.5f) * (1.f / 16.f);
  float ccol = (bx + bw * 0.5f) * (1.f / 16.f);
  int y = p / OW, x = p - (p / OW) * OW;
  float d0 = (float)y - crow, d1 = (float)x - ccol;
  float dist = sqrtf(d0 * d0 + d1 * d1);
  float bins[5];
  #pragma unroll
  for (int b = 0; b < 4; ++b) bins[b] = fmaxf(1.f - fabsf(dist - (float)b), 0.f);
  bins[4] = fminf(fmaxf(dist - 3.f, 0.f), 1.f);
  float lmv = 0.f, mm = 0.f, sp = 0.f;
  #pragma unroll
  for (int b = 0; b < 5; ++b) {
    lmv += bins[b] * label_w[b];
    mm  += bins[b] * mask_w[b];
    sp  += bins[b] * spatial_w[b];
  }
  float tm = 1.f / (1.f + expf(-mm));
  int idx = n * NPIX + p;
  lm[idx]  = lmv;
  sw[idx]  = 0.57735026918962584f * sp;   // sqrt(1/3) * spatial_weight
  alo[idx] = 0.5f * (1.f - tm);
  ahi[idx] = 0.5f * (1.f + tm);
}

// ---------------------------------------------------------------------------
// forward grouped conv on bf16 featB, channel-split partials (unchanged).
// ---------------------------------------------------------------------------
__global__ __launch_bounds__(192) void conv_fwd_part_k(
    const ushort* __restrict__ featB, const float* __restrict__ wsrc,
    float* __restrict__ part)
{
  __shared__ __align__(16) float sfeat[8 * PLSZ];
  int tid = threadIdx.x;
  int n = blockIdx.x;
  int s = n & 63;
  int kc = blockIdx.y;
  const ushort* fbase = featB + ((size_t)n * C_CH + kc * CPB) * HW;
  const float* wbase = wsrc + ((size_t)s * C_CH + kc * CPB) * FT;

  for (int idx = tid; idx < 8 * PLSZ; idx += 192) sfeat[idx] = 0.f;

  int ch_l = tid / 24;
  int row_l = tid - ch_l * 24;
  bool stager = row_l < 18;

  int pos = tid >> 3;
  int slot = tid & 7;
  bool act = pos < 20;
  int cpos = act ? pos : 19;
  int ty = cpos / 5, tx = cpos - (cpos / 5) * 5;

  float acc[5][4];
  #pragma unroll
  for (int r = 0; r < 5; ++r)
    #pragma unroll
    for (int c = 0; c < 4; ++c) acc[r][c] = 0.f;

  const float* plane0 = &sfeat[slot * PLSZ + (5 * ty) * PLW + 4 * tx];
  __syncthreads();

  for (int c0 = 0; c0 < CPB; c0 += 8) {
    if (stager) {
      const uint* src = (const uint*)(fbase + (size_t)(c0 + ch_l) * HW + row_l * 18);
      float* dst = &sfeat[ch_l * PLSZ + (row_l + 2) * PLW + 2];
      #pragma unroll
      for (int k = 0; k < 9; ++k) {
        uint v = src[k];
        float2 w;
        w.x = __uint_as_float(v << 16);
        w.y = __uint_as_float(v & 0xffff0000u);
        *(float2*)(dst + 2 * k) = w;
      }
    }
    __syncthreads();

    const float4* wp = (const float4*)(wbase + (size_t)(c0 + slot) * FT);
    float4 w0 = wp[0], w1 = wp[1], w2 = wp[2], w3 = wp[3];

    #pragma unroll
    for (int ri = 0; ri < 8; ++ri) {
      float4 ra = *(const float4*)(plane0 + ri * PLW);
      float4 rb = *(const float4*)(plane0 + ri * PLW + 4);
      #pragma unroll
      for (int dy = 0; dy < 4; ++dy) {
        int r = ri - dy;
        if (r < 0 || r > 4) continue;
        float4 wr = (dy == 0) ? w0 : (dy == 1) ? w1 : (dy == 2) ? w2 : w3;
        acc[r][0] = fmaf(ra.x, wr.x, acc[r][0]); acc[r][0] = fmaf(ra.y, wr.y, acc[r][0]);
        acc[r][0] = fmaf(ra.z, wr.z, acc[r][0]); acc[r][0] = fmaf(ra.w, wr.w, acc[r][0]);
        acc[r][1] = fmaf(ra.y, wr.x, acc[r][1]); acc[r][1] = fmaf(ra.z, wr.y, acc[r][1]);
        acc[r][1] = fmaf(ra.w, wr.z, acc[r][1]); acc[r][1] = fmaf(rb.x, wr.w, acc[r][1]);
        acc[r][2] = fmaf(ra.z, wr.x, acc[r][2]); acc[r][2] = fmaf(ra.w, wr.y, acc[r][2]);
        acc[r][2] = fmaf(rb.x, wr.z, acc[r][2]); acc[r][2] = fmaf(rb.y, wr.w, acc[r][2]);
        acc[r][3] = fmaf(ra.w, wr.x, acc[r][3]); acc[r][3] = fmaf(rb.x, wr.y, acc[r][3]);
        acc[r][3] = fmaf(rb.y, wr.z, acc[r][3]); acc[r][3] = fmaf(rb.z, wr.w, acc[r][3]);
      }
    }
    __syncthreads();
  }

  #pragma unroll
  for (int r = 0; r < 5; ++r)
    #pragma unroll
    for (int c = 0; c < 4; ++c) {
      float v = acc[r][c];
      v += __shfl_xor(v, 1, 64);
      v += __shfl_xor(v, 2, 64);
      v += __shfl_xor(v, 4, 64);
      acc[r][c] = v;
    }

  int orow = 5 * ty + slot;
  if (act && slot < 5 && orow < OH) {
    float4 v = make_float4(acc[slot][0], acc[slot][1], acc[slot][2], acc[slot][3]);
    *(float4*)(part + ((size_t)n * CSPLIT + kc) * PPIX + orow * 20 + 4 * tx) = v;
  }
}

// ---------------------------------------------------------------------------
// combine0 (once): sum partials -> scores buffer + mask + residuals
// ---------------------------------------------------------------------------
__global__ __launch_bounds__(384) void combine0_k(
    const float* __restrict__ part,
    const float* __restrict__ sw, const float* __restrict__ lm,
    const float* __restrict__ alo, const float* __restrict__ ahi,
    float* __restrict__ scores,
    float* __restrict__ mask, float* __restrict__ rbuf)
{
  int n = blockIdx.x;
  int p = threadIdx.x;
  if (p >= NPIX) return;
  int y = p / OW, x = p - y * OW;
  const float* pb = part + (size_t)n * CSPLIT * PPIX + y * 20 + x;
  float sv = 0.f;
  #pragma unroll
  for (int k = 0; k < CSPLIT; ++k) sv += pb[k * PPIX];
  int idx = n * NPIX + p;
  scores[idx] = sv;
  float lo = alo[idx], hi = ahi[idx], s_w = sw[idx], l_v = lm[idx];
  float sgn = (sv > 0.f) ? 1.f : ((sv < 0.f) ? -1.f : 0.f);
  float actv = lo * fabsf(sv) + hi * sv;
  float msk = lo * sgn + hi;
  mask[idx] = msk;
  rbuf[idx] = msk * s_w * s_w * (actv - l_v);
}

// ---------------------------------------------------------------------------
// transpose conv v2: coalesced bf16 featT [n][p][c] (unchanged).
// ---------------------------------------------------------------------------
__global__ __launch_bounds__(256) void conv_tr2_k(
    const ushort* __restrict__ featT, const float* __restrict__ r,
    float* __restrict__ wgp)
{
  __shared__ __align__(16) float rp[21 * RPW];
  int tid = threadIdx.x;
  int i = blockIdx.x >> 1;
  int cq = blockIdx.x & 1;
  int s = blockIdx.y;
  int cp = tid >> 1, h = tid & 1;
  int c0 = cq * 256 + cp * 2;

  for (int idx = tid; idx < 21 * RPW; idx += 256) rp[idx] = 0.f;
  __syncthreads();
  for (int idx = tid; idx < NPIX; idx += 256) {
    int y = idx / OW, x = idx - y * OW;
    rp[(y + 1) * RPW + (x + 1)] = r[(size_t)(i * S_SEQ + s) * NPIX + idx];
  }
  __syncthreads();

  float acc0[FT], acc1[FT];
  #pragma unroll
  for (int t = 0; t < FT; ++t) { acc0[t] = 0.f; acc1[t] = 0.f; }

  const uint* fbu = (const uint*)featT + (size_t)(i * S_SEQ + s) * HW * (C_CH / 2)
                    + (c0 >> 1);

  for (int uu = 0; uu < 9; ++uu) {
    int u = h * 9 + uu;
    float rw[4][24];
    #pragma unroll
    for (int dy = 0; dy < 4; ++dy) {
      const float4* rr = (const float4*)&rp[(u + 3 - dy) * RPW];
      #pragma unroll
      for (int q = 0; q < 6; ++q) {
        float4 v = rr[q];
        rw[dy][4 * q + 0] = v.x; rw[dy][4 * q + 1] = v.y;
        rw[dy][4 * q + 2] = v.z; rw[dy][4 * q + 3] = v.w;
      }
    }
    uint fv[18];
    #pragma unroll
    for (int v = 0; v < 18; ++v)
      fv[v] = fbu[(size_t)(u * 18 + v) * (C_CH / 2)];
    #pragma unroll
    for (int v = 0; v < 18; ++v) {
      float f0 = __uint_as_float(fv[v] << 16);
      float f1 = __uint_as_float(fv[v] & 0xffff0000u);
      #pragma unroll
      for (int dy = 0; dy < 4; ++dy) {
        #pragma unroll
        for (int dx = 0; dx < 4; ++dx) {
          acc0[dy * 4 + dx] = fmaf(f0, rw[dy][v + 3 - dx], acc0[dy * 4 + dx]);
          acc1[dy * 4 + dx] = fmaf(f1, rw[dy][v + 3 - dx], acc1[dy * 4 + dx]);
        }
      }
    }
  }

  #pragma unroll
  for (int t = 0; t < FT; ++t) {
    acc0[t] += __shfl_xor(acc0[t], 1, 64);
    acc1[t] += __shfl_xor(acc1[t], 1, 64);
  }

  float out[FT];
  #pragma unroll
  for (int t = 0; t < FT; ++t) out[t] = h ? acc1[t] : acc0[t];
  int c = c0 + h;
  float4* dst = (float4*)(wgp + (((size_t)i * S_SEQ + s) * C_CH + c) * FT);
  dst[0] = make_float4(out[0], out[1], out[2], out[3]);
  dst[1] = make_float4(out[4], out[5], out[6], out[7]);
  dst[2] = make_float4(out[8], out[9], out[10], out[11]);
  dst[3] = make_float4(out[12], out[13], out[14], out[15]);
}

// ---------------------------------------------------------------------------
// combine_wg: wg = sum_i wgp + reg*wcur; nump[s] = ||wg||^2
// ---------------------------------------------------------------------------
__global__ __launch_bounds__(256) void combine_wg_k(
    const float* __restrict__ wgp, const float* __restrict__ wcur,
    const float* __restrict__ scal,
    float* __restrict__ wg, float* __restrict__ nump)
{
  __shared__ float rtmp[4];
  int s = blockIdx.x;
  int tid = threadIdx.x;
  float regv = scal[1];
  size_t base = (size_t)s * C_CH * FT;
  size_t istr = (size_t)S_SEQ * C_CH * FT;
  const float4* p0 = (const float4*)(wgp + base);
  const float4* p1 = (const float4*)(wgp + istr + base);
  const float4* p2 = (const float4*)(wgp + 2 * istr + base);
  const float4* pw = (const float4*)(wcur + base);
  float4* pg = (float4*)(wg + base);
  float sq = 0.f;
  for (int g = tid; g < C_CH * FT / 4; g += 256) {
    float4 a = p0[g], b = p1[g], c = p2[g], w = pw[g];
    float4 v;
    v.x = a.x + b.x + c.x + regv * w.x;
    v.y = a.y + b.y + c.y + regv * w.y;
    v.z = a.z + b.z + c.z + regv * w.z;
    v.w = a.w + b.w + c.w + regv * w.w;
    pg[g] = v;
    sq += v.x * v.x + v.y * v.y + v.z * v.z + v.w * v.w;
  }
  float tot = blk_reduce(sq, rtmp);
  if (tid == 0) nump[s] = tot;
}

// ---------------------------------------------------------------------------
// update: den from sg partials, alpha, weight step, incremental scores update,
// next-iteration mask/residuals.
// ---------------------------------------------------------------------------
__global__ __launch_bounds__(256) void update_k(
    float* __restrict__ wcur, const float* __restrict__ wg,
    const float* __restrict__ partb,
    const float* __restrict__ sw, const float* __restrict__ lm,
    const float* __restrict__ alo, const float* __restrict__ ahi,
    float* __restrict__ scores, float* __restrict__ mask,
    float* __restrict__ rbuf,
    const float* __restrict__ nump, const float* __restrict__ scal)
{
  __shared__ float rtmp[4];
  __shared__ float s_sa;
  int s = blockIdx.x;
  int tid = threadIdx.x;

  float sgl[5];
  float sq = 0.f;
  #pragma unroll
  for (int k = 0; k < 5; ++k) {
    int g = tid + k * 256;
    sgl[k] = 0.f;
    if (g < I_IMG * NPIX) {
      int i = g / NPIX, p = g - i * NPIX;
      int n = i * S_SEQ + s;
      int y = p / OW, x = p - y * OW;
      const float* pb = partb + (size_t)n * CSPLIT * PPIX + y * 20 + x;
      float sv = 0.f;
      #pragma unroll
      for (int kk = 0; kk < CSPLIT; ++kk) sv += pb[kk * PPIX];
      sgl[k] = sv;
      int idx = n * NPIX + p;
      float sg = sw[idx] * mask[idx] * sv;
      sq += sg * sg;
    }
  }
  float den = blk_reduce(sq, rtmp);
  if (tid == 0) {
    float num = nump[s];
    float regv = scal[1], step = scal[0];
    float d = fmaxf(den + regv * num, 1e-8f);
    s_sa = step * (num / d);
  }
  __syncthreads();
  float sa = s_sa;

  float4* w4 = (float4*)(wcur + (size_t)s * (C_CH * FT));
  const float4* g4 = (const float4*)(wg + (size_t)s * (C_CH * FT));
  for (int idx = tid; idx < C_CH * FT / 4; idx += 256) {
    float4 w = w4[idx], g = g4[idx];
    w.x -= sa * g.x; w.y -= sa * g.y; w.z -= sa * g.z; w.w -= sa * g.w;
    w4[idx] = w;
  }

  #pragma unroll
  for (int k = 0; k < 5; ++k) {
    int g = tid + k * 256;
    if (g < I_IMG * NPIX) {
      int i = g / NPIX, p = g - i * NPIX;
      int idx = (i * S_SEQ + s) * NPIX + p;
      float sv = scores[idx] - sa * sgl[k];
      scores[idx] = sv;
      float lo = alo[idx], hi = ahi[idx], s_w = sw[idx], l_v = lm[idx];
      float sgn = (sv > 0.f) ? 1.f : ((sv < 0.f) ? -1.f : 0.f);
      float actv = lo * fabsf(sv) + hi * sv;
      float msk = lo * sgn + hi;
      mask[idx] = msk;
      rbuf[idx] = msk * s_w * s_w * (actv - l_v);
    }
  }
}

// ---------------------------------------------------------------------------
extern "C" void kernel_launch(void* const* d_in, const int* in_sizes, int n_in,
                              void* d_out, int out_size, void* d_ws, size_t ws_size,
                              hipStream_t stream)
{
  const float* w_in = (const float*)d_in[0];
  const float* feat = (const float*)d_in[1];
  const float* bb   = (const float*)d_in[2];
  const float* lblw = (const float*)d_in[3];
  const float* mskw = (const float*)d_in[4];
  const float* spw  = (const float*)d_in[5];
  const float* lsl  = (const float*)d_in[6];
  const float* freg = (const float*)d_in[7];

  float* base = (float*)d_ws;
  const int NMAP = I_IMG * S_SEQ * NPIX;   // 69312
  const int NW   = S_SEQ * C_CH * FT;      // 524288
  float* sw     = base;
  float* lm     = sw + NMAP;
  float* alo    = lm + NMAP;
  float* ahi    = alo + NMAP;
  float* mask   = ahi + NMAP;
  float* rbuf   = mask + NMAP;
  float* scores = rbuf + NMAP;
  float* wcur   = scores + NMAP;
  float* wg     = wcur + NW;
  float* wgp    = wg + NW;                 // 3*NW
  float* nump   = wgp + 3 * NW;
  float* scal   = nump + S_SEQ;
  float* partb  = scal + 8;                // I*S*CSPLIT*PPIX = 614400
  ushort* featB = (ushort*)(partb + (size_t)I_IMG * S_SEQ * CSPLIT * PPIX);
  ushort* featT = featB + (size_t)I_IMG * S_SEQ * C_CH * HW;

  convert_k<<<dim3(I_IMG * S_SEQ, 6), 256, 0, stream>>>(feat, featB, featT);
  prep_k<<<I_IMG * S_SEQ, 384, 0, stream>>>(bb, lblw, mskw, spw, lsl, freg,
                                            sw, lm, alo, ahi, scal);
  hipMemcpyAsync(wcur, w_in, (size_t)NW * sizeof(float),
                 hipMemcpyDeviceToDevice, stream);

  // initial scores (only forward conv of wcur)
  conv_fwd_part_k<<<dim3(I_IMG * S_SEQ, CSPLIT), 192, 0, stream>>>(
      featB, wcur, partb);
  combine0_k<<<I_IMG * S_SEQ, 384, 0, stream>>>(
      partb, sw, lm, alo, ahi, scores, mask, rbuf);

  for (int it = 0; it < NITER; ++it) {
    conv_tr2_k<<<dim3(6, S_SEQ), 256, 0, stream>>>(featT, rbuf, wgp);
    combine_wg_k<<<S_SEQ, 256, 0, stream>>>(wgp, wcur, scal, wg, nump);
    conv_fwd_part_k<<<dim3(I_IMG * S_SEQ, CSPLIT), 192, 0, stream>>>(
        featB, wg, partb);
    update_k<<<S_SEQ, 256, 0, stream>>>(
        wcur, wg, partb, sw, lm, alo, ahi, scores, mask, rbuf, nump, scal);
  }
  hipMemcpyAsync(d_out, wcur, (size_t)NW * sizeof(float),
                 hipMemcpyDeviceToDevice, stream);
}

// Round 8
// 518.672 us; speedup vs baseline: 1.1489x; 1.1489x over previous
//
#include <hip/hip_runtime.h>
#include <math.h>

#define I_IMG 3
#define S_SEQ 64
#define C_CH  512
#define H_IN  18
#define W_IN  18
#define HW    324
#define OH 19
#define OW 19
#define NPIX 361
#define PPIX 400          // padded 20x20 partial plane
#define FT 16
#define NITER 5
#define CSPLIT 8
#define CPB 64            // channels per conv_fwd block
#define PLW 24            // fwd LDS plane row stride (floats)
#define PLSZ 580          // fwd LDS plane stride
#define RPW 24            // tr rp row stride
#define CTS 17            // convert LDS row stride (uints)

typedef unsigned int uint;
typedef unsigned short ushort;

__device__ inline float blk_reduce(float v, float* tmp) {
  #pragma unroll
  for (int o = 32; o > 0; o >>= 1) v += __shfl_down(v, o, 64);
  int lane = threadIdx.x & 63;
  int w = threadIdx.x >> 6;
  if (lane == 0) tmp[w] = v;
  __syncthreads();
  float r = 0.f;
  if (threadIdx.x == 0) {
    int nw = (blockDim.x + 63) >> 6;
    for (int k = 0; k < nw; ++k) r += tmp[k];
  }
  return r;
}

__device__ inline uint pack_bf2(float lo, float hi) {  // RNE f32x2 -> packed bf16x2
  uint ul = __float_as_uint(lo);
  uint uh = __float_as_uint(hi);
  ul = (ul + 0x7fffu + ((ul >> 16) & 1u)) >> 16;
  uh = (uh + 0x7fffu + ((uh >> 16) & 1u)) & 0xffff0000u;
  return ul | uh;
}

// ---------------------------------------------------------------------------
// convert: feat f32 [n][c][p] -> featT packed-bf16 [n][p][j], uint j in [0,256)
// packs channels (j, j+256). grid (192, 16): block = (n, 16 uint slots).
// LDS uint[324][17]: stage <=2-way conflicts; output 64B contiguous runs.
// ---------------------------------------------------------------------------
__global__ __launch_bounds__(256) void convert_k(
    const float* __restrict__ feat, ushort* __restrict__ featT)
{
  __shared__ uint tile[HW * CTS];   // 22032 B
  int tid = threadIdx.x;
  int n = blockIdx.x;
  int k0 = blockIdx.y * 16;         // uint-slot base
  const float* fbase = feat + (size_t)n * C_CH * HW;

  // stage: item = (k in 8, q in 81 px-quads); thread packs slots k and k+8
  for (int idx = tid; idx < 8 * 81; idx += 256) {
    int q = idx >> 3;
    int k = idx & 7;
    #pragma unroll
    for (int t = 0; t < 2; ++t) {
      int slot = k + t * 8;
      int j = k0 + slot;
      float4 lo = *(const float4*)(fbase + (size_t)j * HW + 4 * q);
      float4 hi = *(const float4*)(fbase + (size_t)(j + 256) * HW + 4 * q);
      tile[(4 * q + 0) * CTS + slot] = pack_bf2(lo.x, hi.x);
      tile[(4 * q + 1) * CTS + slot] = pack_bf2(lo.y, hi.y);
      tile[(4 * q + 2) * CTS + slot] = pack_bf2(lo.z, hi.z);
      tile[(4 * q + 3) * CTS + slot] = pack_bf2(lo.w, hi.w);
    }
  }
  __syncthreads();

  // output: item = (px, k in 16): 64B contiguous per px
  uint* dT = (uint*)featT + (size_t)n * HW * (C_CH / 2) + k0;
  for (int idx = tid; idx < HW * 16; idx += 256) {
    int px = idx >> 4, k = idx & 15;
    dT[(size_t)px * (C_CH / 2) + k] = tile[px * CTS + k];
  }
}

// ---------------------------------------------------------------------------
// prep: distance map -> label_map, sample_weight, a_lo, a_hi; scalars
// ---------------------------------------------------------------------------
__global__ void prep_k(const float* __restrict__ bb,
                       const float* __restrict__ label_w,
                       const float* __restrict__ mask_w,
                       const float* __restrict__ spatial_w,
                       const float* __restrict__ lsl,
                       const float* __restrict__ freg,
                       float* __restrict__ sw, float* __restrict__ lm,
                       float* __restrict__ alo, float* __restrict__ ahi,
                       float* __restrict__ scal)
{
  int n = blockIdx.x;     // n = i*S + s
  int p = threadIdx.x;
  if (n == 0 && p == 0) {
    scal[0] = expf(lsl[0]);                    // step
    scal[1] = fmaxf(freg[0] * freg[0], 1e-6f); // reg
  }
  if (p >= NPIX) return;
  float bx = bb[n * 4 + 0], by = bb[n * 4 + 1];
  float bw = bb[n * 4 + 2], bh = bb[n * 4 + 3];
  float crow = (by + bh * 0.5f) * (1.f / 16.f);
  float ccol = (bx + bw * 0.5f) * (1.f / 16.f);
  int y = p / OW, x = p - (p / OW) * OW;
  float d0 = (float)y - crow, d1 = (float)x - ccol;
  float dist = sqrtf(d0 * d0 + d1 * d1);
  float bins[5];
  #pragma unroll
  for (int b = 0; b < 4; ++b) bins[b] = fmaxf(1.f - fabsf(dist - (float)b), 0.f);
  bins[4] = fminf(fmaxf(dist - 3.f, 0.f), 1.f);
  float lmv = 0.f, mm = 0.f, sp = 0.f;
  #pragma unroll
  for (int b = 0; b < 5; ++b) {
    lmv += bins[b] * label_w[b];
    mm  += bins[b] * mask_w[b];
    sp  += bins[b] * spatial_w[b];
  }
  float tm = 1.f / (1.f + expf(-mm));
  int idx = n * NPIX + p;
  lm[idx]  = lmv;
  sw[idx]  = 0.57735026918962584f * sp;   // sqrt(1/3) * spatial_weight
  alo[idx] = 0.5f * (1.f - tm);
  ahi[idx] = 0.5f * (1.f + tm);
}

// ---------------------------------------------------------------------------
// forward grouped conv on fp32 feat (R5-proven), channel-split partials.
// ---------------------------------------------------------------------------
__global__ __launch_bounds__(192) void conv_fwd_part_k(
    const float* __restrict__ feat, const float* __restrict__ wsrc,
    float* __restrict__ part)
{
  __shared__ __align__(16) float sfeat[8 * PLSZ];
  int tid = threadIdx.x;
  int n = blockIdx.x;
  int s = n & 63;
  int kc = blockIdx.y;
  const float* fbase = feat + ((size_t)n * C_CH + kc * CPB) * HW;
  const float* wbase = wsrc + ((size_t)s * C_CH + kc * CPB) * FT;

  for (int idx = tid; idx < 8 * PLSZ; idx += 192) sfeat[idx] = 0.f;

  int ch_l = tid / 24;
  int row_l = tid - ch_l * 24;
  bool stager = row_l < 18;

  int pos = tid >> 3;
  int slot = tid & 7;
  bool act = pos < 20;
  int cpos = act ? pos : 19;
  int ty = cpos / 5, tx = cpos - (cpos / 5) * 5;

  float acc[5][4];
  #pragma unroll
  for (int r = 0; r < 5; ++r)
    #pragma unroll
    for (int c = 0; c < 4; ++c) acc[r][c] = 0.f;

  const float* plane0 = &sfeat[slot * PLSZ + (5 * ty) * PLW + 4 * tx];
  __syncthreads();

  for (int c0 = 0; c0 < CPB; c0 += 8) {
    if (stager) {
      const float* src = fbase + (size_t)(c0 + ch_l) * HW + row_l * 18;
      float* dst = &sfeat[ch_l * PLSZ + (row_l + 2) * PLW + 2];
      #pragma unroll
      for (int k = 0; k < 9; ++k) {
        float2 v = *(const float2*)(src + 2 * k);
        *(float2*)(dst + 2 * k) = v;
      }
    }
    __syncthreads();

    const float4* wp = (const float4*)(wbase + (size_t)(c0 + slot) * FT);
    float4 w0 = wp[0], w1 = wp[1], w2 = wp[2], w3 = wp[3];

    #pragma unroll
    for (int ri = 0; ri < 8; ++ri) {
      float4 ra = *(const float4*)(plane0 + ri * PLW);
      float4 rb = *(const float4*)(plane0 + ri * PLW + 4);
      #pragma unroll
      for (int dy = 0; dy < 4; ++dy) {
        int r = ri - dy;
        if (r < 0 || r > 4) continue;
        float4 wr = (dy == 0) ? w0 : (dy == 1) ? w1 : (dy == 2) ? w2 : w3;
        acc[r][0] = fmaf(ra.x, wr.x, acc[r][0]); acc[r][0] = fmaf(ra.y, wr.y, acc[r][0]);
        acc[r][0] = fmaf(ra.z, wr.z, acc[r][0]); acc[r][0] = fmaf(ra.w, wr.w, acc[r][0]);
        acc[r][1] = fmaf(ra.y, wr.x, acc[r][1]); acc[r][1] = fmaf(ra.z, wr.y, acc[r][1]);
        acc[r][1] = fmaf(ra.w, wr.z, acc[r][1]); acc[r][1] = fmaf(rb.x, wr.w, acc[r][1]);
        acc[r][2] = fmaf(ra.z, wr.x, acc[r][2]); acc[r][2] = fmaf(ra.w, wr.y, acc[r][2]);
        acc[r][2] = fmaf(rb.x, wr.z, acc[r][2]); acc[r][2] = fmaf(rb.y, wr.w, acc[r][2]);
        acc[r][3] = fmaf(ra.w, wr.x, acc[r][3]); acc[r][3] = fmaf(rb.x, wr.y, acc[r][3]);
        acc[r][3] = fmaf(rb.y, wr.z, acc[r][3]); acc[r][3] = fmaf(rb.z, wr.w, acc[r][3]);
      }
    }
    __syncthreads();
  }

  #pragma unroll
  for (int r = 0; r < 5; ++r)
    #pragma unroll
    for (int c = 0; c < 4; ++c) {
      float v = acc[r][c];
      v += __shfl_xor(v, 1, 64);
      v += __shfl_xor(v, 2, 64);
      v += __shfl_xor(v, 4, 64);
      acc[r][c] = v;
    }

  int orow = 5 * ty + slot;
  if (act && slot < 5 && orow < OH) {
    float4 v = make_float4(acc[slot][0], acc[slot][1], acc[slot][2], acc[slot][3]);
    *(float4*)(part + ((size_t)n * CSPLIT + kc) * PPIX + orow * 20 + 4 * tx) = v;
  }
}

// ---------------------------------------------------------------------------
// combine0 (once): sum partials -> scores buffer + mask + residuals
// ---------------------------------------------------------------------------
__global__ __launch_bounds__(384) void combine0_k(
    const float* __restrict__ part,
    const float* __restrict__ sw, const float* __restrict__ lm,
    const float* __restrict__ alo, const float* __restrict__ ahi,
    float* __restrict__ scores,
    float* __restrict__ mask, float* __restrict__ rbuf)
{
  int n = blockIdx.x;
  int p = threadIdx.x;
  if (p >= NPIX) return;
  int y = p / OW, x = p - y * OW;
  const float* pb = part + (size_t)n * CSPLIT * PPIX + y * 20 + x;
  float sv = 0.f;
  #pragma unroll
  for (int k = 0; k < CSPLIT; ++k) sv += pb[k * PPIX];
  int idx = n * NPIX + p;
  scores[idx] = sv;
  float lo = alo[idx], hi = ahi[idx], s_w = sw[idx], l_v = lm[idx];
  float sgn = (sv > 0.f) ? 1.f : ((sv < 0.f) ? -1.f : 0.f);
  float actv = lo * fabsf(sv) + hi * sv;
  float msk = lo * sgn + hi;
  mask[idx] = msk;
  rbuf[idx] = msk * s_w * s_w * (actv - l_v);
}

// ---------------------------------------------------------------------------
// transpose conv v2 on packed featT: uint j packs channels (j, j+256).
// grid (6, 64): blockIdx.x = i*2+cq; lane pair covers uint j = cq*128+cp.
// ---------------------------------------------------------------------------
__global__ __launch_bounds__(256) void conv_tr2_k(
    const ushort* __restrict__ featT, const float* __restrict__ r,
    float* __restrict__ wgp)
{
  __shared__ __align__(16) float rp[21 * RPW];
  int tid = threadIdx.x;
  int i = blockIdx.x >> 1;
  int cq = blockIdx.x & 1;
  int s = blockIdx.y;
  int cp = tid >> 1, h = tid & 1;
  int j = cq * 128 + cp;     // uint slot; channels (j, j+256)

  for (int idx = tid; idx < 21 * RPW; idx += 256) rp[idx] = 0.f;
  __syncthreads();
  for (int idx = tid; idx < NPIX; idx += 256) {
    int y = idx / OW, x = idx - y * OW;
    rp[(y + 1) * RPW + (x + 1)] = r[(size_t)(i * S_SEQ + s) * NPIX + idx];
  }
  __syncthreads();

  float acc0[FT], acc1[FT];
  #pragma unroll
  for (int t = 0; t < FT; ++t) { acc0[t] = 0.f; acc1[t] = 0.f; }

  const uint* fbu = (const uint*)featT + (size_t)(i * S_SEQ + s) * HW * (C_CH / 2)
                    + j;

  for (int uu = 0; uu < 9; ++uu) {
    int u = h * 9 + uu;
    float rw[4][24];
    #pragma unroll
    for (int dy = 0; dy < 4; ++dy) {
      const float4* rr = (const float4*)&rp[(u + 3 - dy) * RPW];
      #pragma unroll
      for (int q = 0; q < 6; ++q) {
        float4 v = rr[q];
        rw[dy][4 * q + 0] = v.x; rw[dy][4 * q + 1] = v.y;
        rw[dy][4 * q + 2] = v.z; rw[dy][4 * q + 3] = v.w;
      }
    }
    uint fv[18];
    #pragma unroll
    for (int v = 0; v < 18; ++v)
      fv[v] = fbu[(size_t)(u * 18 + v) * (C_CH / 2)];
    #pragma unroll
    for (int v = 0; v < 18; ++v) {
      float f0 = __uint_as_float(fv[v] << 16);
      float f1 = __uint_as_float(fv[v] & 0xffff0000u);
      #pragma unroll
      for (int dy = 0; dy < 4; ++dy) {
        #pragma unroll
        for (int dx = 0; dx < 4; ++dx) {
          acc0[dy * 4 + dx] = fmaf(f0, rw[dy][v + 3 - dx], acc0[dy * 4 + dx]);
          acc1[dy * 4 + dx] = fmaf(f1, rw[dy][v + 3 - dx], acc1[dy * 4 + dx]);
        }
      }
    }
  }

  #pragma unroll
  for (int t = 0; t < FT; ++t) {
    acc0[t] += __shfl_xor(acc0[t], 1, 64);
    acc1[t] += __shfl_xor(acc1[t], 1, 64);
  }

  // h=0 writes channel j (acc0), h=1 writes j+256 (acc1)
  float out[FT];
  #pragma unroll
  for (int t = 0; t < FT; ++t) out[t] = h ? acc1[t] : acc0[t];
  int c = j + h * 256;
  float4* dst = (float4*)(wgp + (((size_t)i * S_SEQ + s) * C_CH + c) * FT);
  dst[0] = make_float4(out[0], out[1], out[2], out[3]);
  dst[1] = make_float4(out[4], out[5], out[6], out[7]);
  dst[2] = make_float4(out[8], out[9], out[10], out[11]);
  dst[3] = make_float4(out[12], out[13], out[14], out[15]);
}

// ---------------------------------------------------------------------------
// combine_wg: wg = sum_i wgp + reg*wcur; nump[s] = ||wg||^2
// ---------------------------------------------------------------------------
__global__ __launch_bounds__(256) void combine_wg_k(
    const float* __restrict__ wgp, const float* __restrict__ wcur,
    const float* __restrict__ scal,
    float* __restrict__ wg, float* __restrict__ nump)
{
  __shared__ float rtmp[4];
  int s = blockIdx.x;
  int tid = threadIdx.x;
  float regv = scal[1];
  size_t base = (size_t)s * C_CH * FT;
  size_t istr = (size_t)S_SEQ * C_CH * FT;
  const float4* p0 = (const float4*)(wgp + base);
  const float4* p1 = (const float4*)(wgp + istr + base);
  const float4* p2 = (const float4*)(wgp + 2 * istr + base);
  const float4* pw = (const float4*)(wcur + base);
  float4* pg = (float4*)(wg + base);
  float sq = 0.f;
  for (int g = tid; g < C_CH * FT / 4; g += 256) {
    float4 a = p0[g], b = p1[g], c = p2[g], w = pw[g];
    float4 v;
    v.x = a.x + b.x + c.x + regv * w.x;
    v.y = a.y + b.y + c.y + regv * w.y;
    v.z = a.z + b.z + c.z + regv * w.z;
    v.w = a.w + b.w + c.w + regv * w.w;
    pg[g] = v;
    sq += v.x * v.x + v.y * v.y + v.z * v.z + v.w * v.w;
  }
  float tot = blk_reduce(sq, rtmp);
  if (tid == 0) nump[s] = tot;
}

// ---------------------------------------------------------------------------
// update: den from sg partials, alpha, weight step, incremental scores update,
// next-iteration mask/residuals.
// ---------------------------------------------------------------------------
__global__ __launch_bounds__(256) void update_k(
    float* __restrict__ wcur, const float* __restrict__ wg,
    const float* __restrict__ partb,
    const float* __restrict__ sw, const float* __restrict__ lm,
    const float* __restrict__ alo, const float* __restrict__ ahi,
    float* __restrict__ scores, float* __restrict__ mask,
    float* __restrict__ rbuf,
    const float* __restrict__ nump, const float* __restrict__ scal)
{
  __shared__ float rtmp[4];
  __shared__ float s_sa;
  int s = blockIdx.x;
  int tid = threadIdx.x;

  float sgl[5];
  float sq = 0.f;
  #pragma unroll
  for (int k = 0; k < 5; ++k) {
    int g = tid + k * 256;
    sgl[k] = 0.f;
    if (g < I_IMG * NPIX) {
      int i = g / NPIX, p = g - i * NPIX;
      int n = i * S_SEQ + s;
      int y = p / OW, x = p - y * OW;
      const float* pb = partb + (size_t)n * CSPLIT * PPIX + y * 20 + x;
      float sv = 0.f;
      #pragma unroll
      for (int kk = 0; kk < CSPLIT; ++kk) sv += pb[kk * PPIX];
      sgl[k] = sv;
      int idx = n * NPIX + p;
      float sg = sw[idx] * mask[idx] * sv;
      sq += sg * sg;
    }
  }
  float den = blk_reduce(sq, rtmp);
  if (tid == 0) {
    float num = nump[s];
    float regv = scal[1], step = scal[0];
    float d = fmaxf(den + regv * num, 1e-8f);
    s_sa = step * (num / d);
  }
  __syncthreads();
  float sa = s_sa;

  float4* w4 = (float4*)(wcur + (size_t)s * (C_CH * FT));
  const float4* g4 = (const float4*)(wg + (size_t)s * (C_CH * FT));
  for (int idx = tid; idx < C_CH * FT / 4; idx += 256) {
    float4 w = w4[idx], g = g4[idx];
    w.x -= sa * g.x; w.y -= sa * g.y; w.z -= sa * g.z; w.w -= sa * g.w;
    w4[idx] = w;
  }

  #pragma unroll
  for (int k = 0; k < 5; ++k) {
    int g = tid + k * 256;
    if (g < I_IMG * NPIX) {
      int i = g / NPIX, p = g - i * NPIX;
      int idx = (i * S_SEQ + s) * NPIX + p;
      float sv = scores[idx] - sa * sgl[k];
      scores[idx] = sv;
      float lo = alo[idx], hi = ahi[idx], s_w = sw[idx], l_v = lm[idx];
      float sgn = (sv > 0.f) ? 1.f : ((sv < 0.f) ? -1.f : 0.f);
      float actv = lo * fabsf(sv) + hi * sv;
      float msk = lo * sgn + hi;
      mask[idx] = msk;
      rbuf[idx] = msk * s_w * s_w * (actv - l_v);
    }
  }
}

// ---------------------------------------------------------------------------
extern "C" void kernel_launch(void* const* d_in, const int* in_sizes, int n_in,
                              void* d_out, int out_size, void* d_ws, size_t ws_size,
                              hipStream_t stream)
{
  const float* w_in = (const float*)d_in[0];
  const float* feat = (const float*)d_in[1];
  const float* bb   = (const float*)d_in[2];
  const float* lblw = (const float*)d_in[3];
  const float* mskw = (const float*)d_in[4];
  const float* spw  = (const float*)d_in[5];
  const float* lsl  = (const float*)d_in[6];
  const float* freg = (const float*)d_in[7];

  float* base = (float*)d_ws;
  const int NMAP = I_IMG * S_SEQ * NPIX;   // 69312
  const int NW   = S_SEQ * C_CH * FT;      // 524288
  float* sw     = base;
  float* lm     = sw + NMAP;
  float* alo    = lm + NMAP;
  float* ahi    = alo + NMAP;
  float* mask   = ahi + NMAP;
  float* rbuf   = mask + NMAP;
  float* scores = rbuf + NMAP;
  float* wcur   = scores + NMAP;
  float* wg     = wcur + NW;
  float* wgp    = wg + NW;                 // 3*NW
  float* nump   = wgp + 3 * NW;
  float* scal   = nump + S_SEQ;
  float* partb  = scal + 8;                // I*S*CSPLIT*PPIX = 614400
  ushort* featT = (ushort*)(partb + (size_t)I_IMG * S_SEQ * CSPLIT * PPIX);

  convert_k<<<dim3(I_IMG * S_SEQ, 16), 256, 0, stream>>>(feat, featT);
  prep_k<<<I_IMG * S_SEQ, 384, 0, stream>>>(bb, lblw, mskw, spw, lsl, freg,
                                            sw, lm, alo, ahi, scal);
  hipMemcpyAsync(wcur, w_in, (size_t)NW * sizeof(float),
                 hipMemcpyDeviceToDevice, stream);

  // initial scores (only forward conv of wcur)
  conv_fwd_part_k<<<dim3(I_IMG * S_SEQ, CSPLIT), 192, 0, stream>>>(
      feat, wcur, partb);
  combine0_k<<<I_IMG * S_SEQ, 384, 0, stream>>>(
      partb, sw, lm, alo, ahi, scores, mask, rbuf);

  for (int it = 0; it < NITER; ++it) {
    conv_tr2_k<<<dim3(6, S_SEQ), 256, 0, stream>>>(featT, rbuf, wgp);
    combine_wg_k<<<S_SEQ, 256, 0, stream>>>(wgp, wcur, scal, wg, nump);
    conv_fwd_part_k<<<dim3(I_IMG * S_SEQ, CSPLIT), 192, 0, stream>>>(
        feat, wg, partb);
    update_k<<<S_SEQ, 256, 0, stream>>>(
        wcur, wg, partb, sw, lm, alo, ahi, scores, mask, rbuf, nump, scal);
  }
  hipMemcpyAsync(d_out, wcur, (size_t)NW * sizeof(float),
                 hipMemcpyDeviceToDevice, stream);
}

// Round 9
// 515.209 us; speedup vs baseline: 1.1566x; 1.0067x over previous
//
#include <hip/hip_runtime.h>
#include <math.h>

#define I_IMG 3
#define S_SEQ 64
#define C_CH  512
#define H_IN  18
#define W_IN  18
#define HW    324
#define OH 19
#define OW 19
#define NPIX 361
#define PPIX 400          // padded 20x20 partial plane
#define FT 16
#define NITER 5
#define CSPLIT 8
#define CPB 64            // channels per conv_fwd block
#define PLW 24            // fwd LDS plane row stride (floats)
#define PLSZ 580          // fwd LDS plane stride
#define RPW 24            // tr rp row stride
#define CVS 32            // uint slots per convert block

typedef unsigned int uint;
typedef unsigned short ushort;

__device__ inline float blk_reduce(float v, float* tmp) {
  #pragma unroll
  for (int o = 32; o > 0; o >>= 1) v += __shfl_down(v, o, 64);
  int lane = threadIdx.x & 63;
  int w = threadIdx.x >> 6;
  if (lane == 0) tmp[w] = v;
  __syncthreads();
  float r = 0.f;
  if (threadIdx.x == 0) {
    int nw = (blockDim.x + 63) >> 6;
    for (int k = 0; k < nw; ++k) r += tmp[k];
  }
  return r;
}

__device__ inline uint pack_bf2(float lo, float hi) {  // RNE f32x2 -> packed bf16x2
  uint ul = __float_as_uint(lo);
  uint uh = __float_as_uint(hi);
  ul = (ul + 0x7fffu + ((ul >> 16) & 1u)) >> 16;
  uh = (uh + 0x7fffu + ((uh >> 16) & 1u)) & 0xffff0000u;
  return ul | uh;
}

// ---------------------------------------------------------------------------
// convert: feat f32 [n][c][p] -> featT packed-bf16 [n][p][j], uint j in [0,256)
// packs channels (j, j+256). grid (192, 8): block = (n, 32 uint slots).
// Reads: full 1296B channel rows (coalesced). Writes: 128B full lines per px.
// ---------------------------------------------------------------------------
__global__ __launch_bounds__(256) void convert_k(
    const float* __restrict__ feat, ushort* __restrict__ featT)
{
  __shared__ __align__(16) uint tile[HW * CVS];   // 41472 B
  int tid = threadIdx.x;
  int n = blockIdx.x;
  int k0 = blockIdx.y * CVS;
  const float* fbase = feat + (size_t)n * C_CH * HW;

  // stage: item = (q in 81 px-quads, k in 32 slots)
  for (int idx = tid; idx < 81 * CVS; idx += 256) {
    int k = idx & 31, q = idx >> 5;
    int j = k0 + k;
    float4 lo = *(const float4*)(fbase + (size_t)j * HW + 4 * q);
    float4 hi = *(const float4*)(fbase + (size_t)(j + 256) * HW + 4 * q);
    tile[(4 * q + 0) * CVS + k] = pack_bf2(lo.x, hi.x);
    tile[(4 * q + 1) * CVS + k] = pack_bf2(lo.y, hi.y);
    tile[(4 * q + 2) * CVS + k] = pack_bf2(lo.z, hi.z);
    tile[(4 * q + 3) * CVS + k] = pack_bf2(lo.w, hi.w);
  }
  __syncthreads();

  // output: item = (px, g in 8 uint4-groups): 8 lanes cover a 128B line
  uint* dTb = (uint*)featT + (size_t)n * HW * (C_CH / 2) + k0;
  const uint4* t4 = (const uint4*)tile;
  for (int idx = tid; idx < HW * 8; idx += 256) {
    int px = idx >> 3, g = idx & 7;
    *(uint4*)(dTb + (size_t)px * (C_CH / 2) + 4 * g) = t4[idx];
  }
}

// ---------------------------------------------------------------------------
// prep: distance map -> label_map, sample_weight, a_lo, a_hi; scalars
// ---------------------------------------------------------------------------
__global__ void prep_k(const float* __restrict__ bb,
                       const float* __restrict__ label_w,
                       const float* __restrict__ mask_w,
                       const float* __restrict__ spatial_w,
                       const float* __restrict__ lsl,
                       const float* __restrict__ freg,
                       float* __restrict__ sw, float* __restrict__ lm,
                       float* __restrict__ alo, float* __restrict__ ahi,
                       float* __restrict__ scal)
{
  int n = blockIdx.x;     // n = i*S + s
  int p = threadIdx.x;
  if (n == 0 && p == 0) {
    scal[0] = expf(lsl[0]);                    // step
    scal[1] = fmaxf(freg[0] * freg[0], 1e-6f); // reg
  }
  if (p >= NPIX) return;
  float bx = bb[n * 4 + 0], by = bb[n * 4 + 1];
  float bw = bb[n * 4 + 2], bh = bb[n * 4 + 3];
  float crow = (by + bh * 0.5f) * (1.f / 16.f);
  float ccol = (bx + bw * 0.5f) * (1.f / 16.f);
  int y = p / OW, x = p - (p / OW) * OW;
  float d0 = (float)y - crow, d1 = (float)x - ccol;
  float dist = sqrtf(d0 * d0 + d1 * d1);
  float bins[5];
  #pragma unroll
  for (int b = 0; b < 4; ++b) bins[b] = fmaxf(1.f - fabsf(dist - (float)b), 0.f);
  bins[4] = fminf(fmaxf(dist - 3.f, 0.f), 1.f);
  float lmv = 0.f, mm = 0.f, sp = 0.f;
  #pragma unroll
  for (int b = 0; b < 5; ++b) {
    lmv += bins[b] * label_w[b];
    mm  += bins[b] * mask_w[b];
    sp  += bins[b] * spatial_w[b];
  }
  float tm = 1.f / (1.f + expf(-mm));
  int idx = n * NPIX + p;
  lm[idx]  = lmv;
  sw[idx]  = 0.57735026918962584f * sp;   // sqrt(1/3) * spatial_weight
  alo[idx] = 0.5f * (1.f - tm);
  ahi[idx] = 0.5f * (1.f + tm);
}

// ---------------------------------------------------------------------------
// forward grouped conv on fp32 feat (R5-proven), channel-split partials.
// ---------------------------------------------------------------------------
__global__ __launch_bounds__(192) void conv_fwd_part_k(
    const float* __restrict__ feat, const float* __restrict__ wsrc,
    float* __restrict__ part)
{
  __shared__ __align__(16) float sfeat[8 * PLSZ];
  int tid = threadIdx.x;
  int n = blockIdx.x;
  int s = n & 63;
  int kc = blockIdx.y;
  const float* fbase = feat + ((size_t)n * C_CH + kc * CPB) * HW;
  const float* wbase = wsrc + ((size_t)s * C_CH + kc * CPB) * FT;

  for (int idx = tid; idx < 8 * PLSZ; idx += 192) sfeat[idx] = 0.f;

  int ch_l = tid / 24;
  int row_l = tid - ch_l * 24;
  bool stager = row_l < 18;

  int pos = tid >> 3;
  int slot = tid & 7;
  bool act = pos < 20;
  int cpos = act ? pos : 19;
  int ty = cpos / 5, tx = cpos - (cpos / 5) * 5;

  float acc[5][4];
  #pragma unroll
  for (int r = 0; r < 5; ++r)
    #pragma unroll
    for (int c = 0; c < 4; ++c) acc[r][c] = 0.f;

  const float* plane0 = &sfeat[slot * PLSZ + (5 * ty) * PLW + 4 * tx];
  __syncthreads();

  for (int c0 = 0; c0 < CPB; c0 += 8) {
    if (stager) {
      const float* src = fbase + (size_t)(c0 + ch_l) * HW + row_l * 18;
      float* dst = &sfeat[ch_l * PLSZ + (row_l + 2) * PLW + 2];
      #pragma unroll
      for (int k = 0; k < 9; ++k) {
        float2 v = *(const float2*)(src + 2 * k);
        *(float2*)(dst + 2 * k) = v;
      }
    }
    __syncthreads();

    const float4* wp = (const float4*)(wbase + (size_t)(c0 + slot) * FT);
    float4 w0 = wp[0], w1 = wp[1], w2 = wp[2], w3 = wp[3];

    #pragma unroll
    for (int ri = 0; ri < 8; ++ri) {
      float4 ra = *(const float4*)(plane0 + ri * PLW);
      float4 rb = *(const float4*)(plane0 + ri * PLW + 4);
      #pragma unroll
      for (int dy = 0; dy < 4; ++dy) {
        int r = ri - dy;
        if (r < 0 || r > 4) continue;
        float4 wr = (dy == 0) ? w0 : (dy == 1) ? w1 : (dy == 2) ? w2 : w3;
        acc[r][0] = fmaf(ra.x, wr.x, acc[r][0]); acc[r][0] = fmaf(ra.y, wr.y, acc[r][0]);
        acc[r][0] = fmaf(ra.z, wr.z, acc[r][0]); acc[r][0] = fmaf(ra.w, wr.w, acc[r][0]);
        acc[r][1] = fmaf(ra.y, wr.x, acc[r][1]); acc[r][1] = fmaf(ra.z, wr.y, acc[r][1]);
        acc[r][1] = fmaf(ra.w, wr.z, acc[r][1]); acc[r][1] = fmaf(rb.x, wr.w, acc[r][1]);
        acc[r][2] = fmaf(ra.z, wr.x, acc[r][2]); acc[r][2] = fmaf(ra.w, wr.y, acc[r][2]);
        acc[r][2] = fmaf(rb.x, wr.z, acc[r][2]); acc[r][2] = fmaf(rb.y, wr.w, acc[r][2]);
        acc[r][3] = fmaf(ra.w, wr.x, acc[r][3]); acc[r][3] = fmaf(rb.x, wr.y, acc[r][3]);
        acc[r][3] = fmaf(rb.y, wr.z, acc[r][3]); acc[r][3] = fmaf(rb.z, wr.w, acc[r][3]);
      }
    }
    __syncthreads();
  }

  #pragma unroll
  for (int r = 0; r < 5; ++r)
    #pragma unroll
    for (int c = 0; c < 4; ++c) {
      float v = acc[r][c];
      v += __shfl_xor(v, 1, 64);
      v += __shfl_xor(v, 2, 64);
      v += __shfl_xor(v, 4, 64);
      acc[r][c] = v;
    }

  int orow = 5 * ty + slot;
  if (act && slot < 5 && orow < OH) {
    float4 v = make_float4(acc[slot][0], acc[slot][1], acc[slot][2], acc[slot][3]);
    *(float4*)(part + ((size_t)n * CSPLIT + kc) * PPIX + orow * 20 + 4 * tx) = v;
  }
}

// ---------------------------------------------------------------------------
// combine0 (once): sum partials -> scores buffer + mask + residuals
// ---------------------------------------------------------------------------
__global__ __launch_bounds__(384) void combine0_k(
    const float* __restrict__ part,
    const float* __restrict__ sw, const float* __restrict__ lm,
    const float* __restrict__ alo, const float* __restrict__ ahi,
    float* __restrict__ scores,
    float* __restrict__ mask, float* __restrict__ rbuf)
{
  int n = blockIdx.x;
  int p = threadIdx.x;
  if (p >= NPIX) return;
  int y = p / OW, x = p - y * OW;
  const float* pb = part + (size_t)n * CSPLIT * PPIX + y * 20 + x;
  float sv = 0.f;
  #pragma unroll
  for (int k = 0; k < CSPLIT; ++k) sv += pb[k * PPIX];
  int idx = n * NPIX + p;
  scores[idx] = sv;
  float lo = alo[idx], hi = ahi[idx], s_w = sw[idx], l_v = lm[idx];
  float sgn = (sv > 0.f) ? 1.f : ((sv < 0.f) ? -1.f : 0.f);
  float actv = lo * fabsf(sv) + hi * sv;
  float msk = lo * sgn + hi;
  mask[idx] = msk;
  rbuf[idx] = msk * s_w * s_w * (actv - l_v);
}

// ---------------------------------------------------------------------------
// transpose conv v2 on packed featT: uint j packs channels (j, j+256).
// grid (6, 64): blockIdx.x = i*2+cq; lane pair covers uint j = cq*128+cp.
// ---------------------------------------------------------------------------
__global__ __launch_bounds__(256) void conv_tr2_k(
    const ushort* __restrict__ featT, const float* __restrict__ r,
    float* __restrict__ wgp)
{
  __shared__ __align__(16) float rp[21 * RPW];
  int tid = threadIdx.x;
  int i = blockIdx.x >> 1;
  int cq = blockIdx.x & 1;
  int s = blockIdx.y;
  int cp = tid >> 1, h = tid & 1;
  int j = cq * 128 + cp;     // uint slot; channels (j, j+256)

  for (int idx = tid; idx < 21 * RPW; idx += 256) rp[idx] = 0.f;
  __syncthreads();
  for (int idx = tid; idx < NPIX; idx += 256) {
    int y = idx / OW, x = idx - y * OW;
    rp[(y + 1) * RPW + (x + 1)] = r[(size_t)(i * S_SEQ + s) * NPIX + idx];
  }
  __syncthreads();

  float acc0[FT], acc1[FT];
  #pragma unroll
  for (int t = 0; t < FT; ++t) { acc0[t] = 0.f; acc1[t] = 0.f; }

  const uint* fbu = (const uint*)featT + (size_t)(i * S_SEQ + s) * HW * (C_CH / 2)
                    + j;

  for (int uu = 0; uu < 9; ++uu) {
    int u = h * 9 + uu;
    float rw[4][24];
    #pragma unroll
    for (int dy = 0; dy < 4; ++dy) {
      const float4* rr = (const float4*)&rp[(u + 3 - dy) * RPW];
      #pragma unroll
      for (int q = 0; q < 6; ++q) {
        float4 v = rr[q];
        rw[dy][4 * q + 0] = v.x; rw[dy][4 * q + 1] = v.y;
        rw[dy][4 * q + 2] = v.z; rw[dy][4 * q + 3] = v.w;
      }
    }
    uint fv[18];
    #pragma unroll
    for (int v = 0; v < 18; ++v)
      fv[v] = fbu[(size_t)(u * 18 + v) * (C_CH / 2)];
    #pragma unroll
    for (int v = 0; v < 18; ++v) {
      float f0 = __uint_as_float(fv[v] << 16);
      float f1 = __uint_as_float(fv[v] & 0xffff0000u);
      #pragma unroll
      for (int dy = 0; dy < 4; ++dy) {
        #pragma unroll
        for (int dx = 0; dx < 4; ++dx) {
          acc0[dy * 4 + dx] = fmaf(f0, rw[dy][v + 3 - dx], acc0[dy * 4 + dx]);
          acc1[dy * 4 + dx] = fmaf(f1, rw[dy][v + 3 - dx], acc1[dy * 4 + dx]);
        }
      }
    }
  }

  #pragma unroll
  for (int t = 0; t < FT; ++t) {
    acc0[t] += __shfl_xor(acc0[t], 1, 64);
    acc1[t] += __shfl_xor(acc1[t], 1, 64);
  }

  // h=0 writes channel j (acc0), h=1 writes j+256 (acc1)
  float out[FT];
  #pragma unroll
  for (int t = 0; t < FT; ++t) out[t] = h ? acc1[t] : acc0[t];
  int c = j + h * 256;
  float4* dst = (float4*)(wgp + (((size_t)i * S_SEQ + s) * C_CH + c) * FT);
  dst[0] = make_float4(out[0], out[1], out[2], out[3]);
  dst[1] = make_float4(out[4], out[5], out[6], out[7]);
  dst[2] = make_float4(out[8], out[9], out[10], out[11]);
  dst[3] = make_float4(out[12], out[13], out[14], out[15]);
}

// ---------------------------------------------------------------------------
// combine_wg: wg = sum_i wgp + reg*wcur; nump[s] = ||wg||^2
// ---------------------------------------------------------------------------
__global__ __launch_bounds__(256) void combine_wg_k(
    const float* __restrict__ wgp, const float* __restrict__ wcur,
    const float* __restrict__ scal,
    float* __restrict__ wg, float* __restrict__ nump)
{
  __shared__ float rtmp[4];
  int s = blockIdx.x;
  int tid = threadIdx.x;
  float regv = scal[1];
  size_t base = (size_t)s * C_CH * FT;
  size_t istr = (size_t)S_SEQ * C_CH * FT;
  const float4* p0 = (const float4*)(wgp + base);
  const float4* p1 = (const float4*)(wgp + istr + base);
  const float4* p2 = (const float4*)(wgp + 2 * istr + base);
  const float4* pw = (const float4*)(wcur + base);
  float4* pg = (float4*)(wg + base);
  float sq = 0.f;
  for (int g = tid; g < C_CH * FT / 4; g += 256) {
    float4 a = p0[g], b = p1[g], c = p2[g], w = pw[g];
    float4 v;
    v.x = a.x + b.x + c.x + regv * w.x;
    v.y = a.y + b.y + c.y + regv * w.y;
    v.z = a.z + b.z + c.z + regv * w.z;
    v.w = a.w + b.w + c.w + regv * w.w;
    pg[g] = v;
    sq += v.x * v.x + v.y * v.y + v.z * v.z + v.w * v.w;
  }
  float tot = blk_reduce(sq, rtmp);
  if (tid == 0) nump[s] = tot;
}

// ---------------------------------------------------------------------------
// update: den from sg partials, alpha, weight step, incremental scores update,
// next-iteration mask/residuals.
// ---------------------------------------------------------------------------
__global__ __launch_bounds__(256) void update_k(
    float* __restrict__ wcur, const float* __restrict__ wg,
    const float* __restrict__ partb,
    const float* __restrict__ sw, const float* __restrict__ lm,
    const float* __restrict__ alo, const float* __restrict__ ahi,
    float* __restrict__ scores, float* __restrict__ mask,
    float* __restrict__ rbuf,
    const float* __restrict__ nump, const float* __restrict__ scal)
{
  __shared__ float rtmp[4];
  __shared__ float s_sa;
  int s = blockIdx.x;
  int tid = threadIdx.x;

  float sgl[5];
  float sq = 0.f;
  #pragma unroll
  for (int k = 0; k < 5; ++k) {
    int g = tid + k * 256;
    sgl[k] = 0.f;
    if (g < I_IMG * NPIX) {
      int i = g / NPIX, p = g - i * NPIX;
      int n = i * S_SEQ + s;
      int y = p / OW, x = p - y * OW;
      const float* pb = partb + (size_t)n * CSPLIT * PPIX + y * 20 + x;
      float sv = 0.f;
      #pragma unroll
      for (int kk = 0; kk < CSPLIT; ++kk) sv += pb[kk * PPIX];
      sgl[k] = sv;
      int idx = n * NPIX + p;
      float sg = sw[idx] * mask[idx] * sv;
      sq += sg * sg;
    }
  }
  float den = blk_reduce(sq, rtmp);
  if (tid == 0) {
    float num = nump[s];
    float regv = scal[1], step = scal[0];
    float d = fmaxf(den + regv * num, 1e-8f);
    s_sa = step * (num / d);
  }
  __syncthreads();
  float sa = s_sa;

  float4* w4 = (float4*)(wcur + (size_t)s * (C_CH * FT));
  const float4* g4 = (const float4*)(wg + (size_t)s * (C_CH * FT));
  for (int idx = tid; idx < C_CH * FT / 4; idx += 256) {
    float4 w = w4[idx], g = g4[idx];
    w.x -= sa * g.x; w.y -= sa * g.y; w.z -= sa * g.z; w.w -= sa * g.w;
    w4[idx] = w;
  }

  #pragma unroll
  for (int k = 0; k < 5; ++k) {
    int g = tid + k * 256;
    if (g < I_IMG * NPIX) {
      int i = g / NPIX, p = g - i * NPIX;
      int idx = (i * S_SEQ + s) * NPIX + p;
      float sv = scores[idx] - sa * sgl[k];
      scores[idx] = sv;
      float lo = alo[idx], hi = ahi[idx], s_w = sw[idx], l_v = lm[idx];
      float sgn = (sv > 0.f) ? 1.f : ((sv < 0.f) ? -1.f : 0.f);
      float actv = lo * fabsf(sv) + hi * sv;
      float msk = lo * sgn + hi;
      mask[idx] = msk;
      rbuf[idx] = msk * s_w * s_w * (actv - l_v);
    }
  }
}

// ---------------------------------------------------------------------------
extern "C" void kernel_launch(void* const* d_in, const int* in_sizes, int n_in,
                              void* d_out, int out_size, void* d_ws, size_t ws_size,
                              hipStream_t stream)
{
  const float* w_in = (const float*)d_in[0];
  const float* feat = (const float*)d_in[1];
  const float* bb   = (const float*)d_in[2];
  const float* lblw = (const float*)d_in[3];
  const float* mskw = (const float*)d_in[4];
  const float* spw  = (const float*)d_in[5];
  const float* lsl  = (const float*)d_in[6];
  const float* freg = (const float*)d_in[7];

  float* base = (float*)d_ws;
  const int NMAP = I_IMG * S_SEQ * NPIX;   // 69312
  const int NW   = S_SEQ * C_CH * FT;      // 524288
  float* sw     = base;
  float* lm     = sw + NMAP;
  float* alo    = lm + NMAP;
  float* ahi    = alo + NMAP;
  float* mask   = ahi + NMAP;
  float* rbuf   = mask + NMAP;
  float* scores = rbuf + NMAP;
  float* wcur   = scores + NMAP;
  float* wg     = wcur + NW;
  float* wgp    = wg + NW;                 // 3*NW
  float* nump   = wgp + 3 * NW;
  float* scal   = nump + S_SEQ;
  float* partb  = scal + 8;                // I*S*CSPLIT*PPIX = 614400
  ushort* featT = (ushort*)(partb + (size_t)I_IMG * S_SEQ * CSPLIT * PPIX);

  convert_k<<<dim3(I_IMG * S_SEQ, 8), 256, 0, stream>>>(feat, featT);
  prep_k<<<I_IMG * S_SEQ, 384, 0, stream>>>(bb, lblw, mskw, spw, lsl, freg,
                                            sw, lm, alo, ahi, scal);
  hipMemcpyAsync(wcur, w_in, (size_t)NW * sizeof(float),
                 hipMemcpyDeviceToDevice, stream);

  // initial scores (only forward conv of wcur)
  conv_fwd_part_k<<<dim3(I_IMG * S_SEQ, CSPLIT), 192, 0, stream>>>(
      feat, wcur, partb);
  combine0_k<<<I_IMG * S_SEQ, 384, 0, stream>>>(
      partb, sw, lm, alo, ahi, scores, mask, rbuf);

  for (int it = 0; it < NITER; ++it) {
    conv_tr2_k<<<dim3(6, S_SEQ), 256, 0, stream>>>(featT, rbuf, wgp);
    combine_wg_k<<<S_SEQ, 256, 0, stream>>>(wgp, wcur, scal, wg, nump);
    conv_fwd_part_k<<<dim3(I_IMG * S_SEQ, CSPLIT), 192, 0, stream>>>(
        feat, wg, partb);
    update_k<<<S_SEQ, 256, 0, stream>>>(
        wcur, wg, partb, sw, lm, alo, ahi, scores, mask, rbuf, nump, scal);
  }
  hipMemcpyAsync(d_out, wcur, (size_t)NW * sizeof(float),
                 hipMemcpyDeviceToDevice, stream);
}